// Round 1
// baseline (710.292 us; speedup 1.0000x reference)
//
#include <hip/hip_runtime.h>

// cost volume: out[n,h,w,9*dh+dw] = (1/128) * sum_c f1[n,h,w,c]*f2[n,h+dh-4,w+dw-4,c]
// N=8 H=128 W=256 C=128, zero-padded f2 borders.

#define NN 8
#define HH 128
#define WW 256
#define CC 128

constexpr int WT   = 128;   // w-tile per workgroup
constexpr int P    = 8;     // pixels per group (register tile)
constexpr int S    = 16;    // c-split slots
constexpr int KC   = 16;    // c per staged block
constexpr int NCB  = CC / KC;         // 8
constexpr int F2W  = WT + 8;          // 136 staged x positions
constexpr int F2ST = 140;             // padded row stride (floats), mult of 4, 140%32=12 spreads banks
constexpr int LDSF = 36 * 256;        // 9216 floats = 36 KB (> 16*140=2240 staging floats)

__global__ __launch_bounds__(256, 3)
void cost_volume_kernel(const float* __restrict__ f1,
                        const float* __restrict__ f2,
                        float* __restrict__ out) {
    __shared__ __align__(16) float lds[LDSF];

    const int t  = threadIdx.x;
    const int g  = t >> 4;      // 0..15 pixel-group
    const int s  = t & 15;      // 0..15 c-slot
    const int p0 = g * P;       // local pixel base 0..120

    // block swizzle: give each XCD (b&7) a contiguous 16-row h-chunk for f2 L2 reuse
    int b   = blockIdx.x;
    int xcd = b & 7;
    int i   = b >> 3;            // 0..255
    int wt  = i & 1;
    int h   = (xcd << 4) | ((i >> 1) & 15);
    int n   = i >> 5;            // 0..7
    const int w0 = wt * WT;

    const float* f1row = f1 + (((long)(n * HH) + h) * WW + w0) * CC;

    for (int dh = 0; dh < 9; ++dh) {
        const int y = h + dh - 4;
        const bool valid = (y >= 0 && y < HH);   // workgroup-uniform

        float acc[72];
        #pragma unroll
        for (int a = 0; a < 72; ++a) acc[a] = 0.f;

        if (valid) {
            const float* f2row = f2 + (((long)(n * HH) + y) * WW) * CC;
            for (int cb = 0; cb < NCB; ++cb) {
                const int c0 = cb * KC;
                __syncthreads();   // protect LDS (prev compute reads / reduction)
                // ---- stage f2T[cc][x+4] via 4x4 register transpose blocks ----
                // 34 x-blocks * 4 c-quads = 136 blocks
                if (t < 136) {
                    const int c4 = t & 3;
                    const int xb = t >> 2;          // 0..33
                    const int x0 = xb * 4 - 4;      // local x base, covers x0..x0+3
                    float4 v[4];
                    #pragma unroll
                    for (int ii = 0; ii < 4; ++ii) {
                        const int xg = w0 + x0 + ii;
                        if (xg >= 0 && xg < WW) {
                            v[ii] = *(const float4*)(f2row + (long)xg * CC + c0 + c4 * 4);
                        } else {
                            v[ii] = make_float4(0.f, 0.f, 0.f, 0.f);
                        }
                    }
                    #pragma unroll
                    for (int j = 0; j < 4; ++j) {
                        float4 w4;
                        w4.x = ((const float*)&v[0])[j];
                        w4.y = ((const float*)&v[1])[j];
                        w4.z = ((const float*)&v[2])[j];
                        w4.w = ((const float*)&v[3])[j];
                        *(float4*)&lds[(c4 * 4 + j) * F2ST + (x0 + 4)] = w4;
                    }
                }
                __syncthreads();
                // ---- compute: this thread's c = c0 + s ----
                float fb[16];
                #pragma unroll
                for (int q = 0; q < 4; ++q)
                    *(float4*)&fb[q * 4] = *(const float4*)&lds[s * F2ST + p0 + q * 4];
                float fa[8];
                #pragma unroll
                for (int k = 0; k < 8; ++k)
                    fa[k] = f1row[(p0 + k) * CC + c0 + s];
                #pragma unroll
                for (int k = 0; k < 8; ++k) {
                    #pragma unroll
                    for (int dw = 0; dw < 9; ++dw)
                        acc[k * 9 + dw] += fa[k] * fb[k + dw];
                }
            }
        }

        // ---- reduce over 16 c-slots + store; two pixel halves to fit 36 KB ----
        #pragma unroll
        for (int h2 = 0; h2 < 2; ++h2) {
            __syncthreads();
            #pragma unroll
            for (int kk = 0; kk < 4; ++kk) {
                #pragma unroll
                for (int dw = 0; dw < 9; ++dw)
                    lds[(kk * 9 + dw) * 256 + t] = acc[(h2 * 4 + kk) * 9 + dw];
            }
            __syncthreads();
            if (t < 128) {
                const int pair = t >> 1;     // 0..63
                const int g2   = pair >> 2;  // 0..15
                const int kk   = pair & 3;
                const int part = t & 1;
                const int px   = g2 * 8 + h2 * 4 + kk;
                float* outp = out + (((long)(n * HH) + h) * WW + w0 + px) * 81 + dh * 9;
                const int dwlo = part ? 5 : 0;
                const int dwhi = part ? 9 : 5;
                for (int dw = dwlo; dw < dwhi; ++dw) {
                    const float* r = &lds[(kk * 9 + dw) * 256 + g2 * 16];
                    float4 a0 = *(const float4*)(r);
                    float4 a1 = *(const float4*)(r + 4);
                    float4 a2 = *(const float4*)(r + 8);
                    float4 a3 = *(const float4*)(r + 12);
                    float sum = (((a0.x + a0.y) + (a0.z + a0.w)) + ((a1.x + a1.y) + (a1.z + a1.w)))
                              + (((a2.x + a2.y) + (a2.z + a2.w)) + ((a3.x + a3.y) + (a3.z + a3.w)));
                    outp[dw] = sum * (1.0f / 128.0f);
                }
            }
        }
    }
}

extern "C" void kernel_launch(void* const* d_in, const int* in_sizes, int n_in,
                              void* d_out, int out_size, void* d_ws, size_t ws_size,
                              hipStream_t stream) {
    const float* f1 = (const float*)d_in[0];
    const float* f2 = (const float*)d_in[1];
    float* out = (float*)d_out;
    dim3 grid(NN * HH * 2);   // 2048 workgroups
    dim3 block(256);
    cost_volume_kernel<<<grid, block, 0, stream>>>(f1, f2, out);
}